// Round 12
// baseline (298.081 us; speedup 1.0000x reference)
//
#include <hip/hip_runtime.h>

// x (B,K,D) f32, w (1,K,D) f32 -> out (S*B, K, D) f32
// out[s*B+b, k, d] = exp(-d2[b,d] * inv[s]),  d2[b,d] = sum_k (x[b,k,d]-w[k,d])^2
//
// Two-phase: A computes kv[s][b][d] (5.24 MB) into d_ws reading x exactly once;
// B broadcasts kv to out with fully block-sequential writes (fill-shaped:
// the harness's own 1.028 GB fill sustains 6.2 TB/s with this pattern, while
// round-7/11 scattered 2KB-burst writes measured only ~2.4 TB/s; NT vs plain
// stores was null, implicating DRAM-level address scatter, not the L2 path).
#define BB 128
#define KK 49
#define DD 2048
#define SS 5

typedef float f32x2 __attribute__((ext_vector_type(2)));
typedef float f32x4 __attribute__((ext_vector_type(4)));

__global__ __launch_bounds__(256) void rbf_kv_kernel(
    const float* __restrict__ x, const float* __restrict__ w,
    float* __restrict__ kv) {
  // grid = BB*4; each thread owns one f32x2 of (b, d).
  const int chunk = blockIdx.x & 3;
  const int b     = blockIdx.x >> 2;
  const int d2i   = chunk * 256 + threadIdx.x;   // f32x2 index in [0, 1024)

  const f32x2* xp = (const f32x2*)x + (size_t)b * (KK * (DD / 2)) + d2i;
  const f32x2* wp = (const f32x2*)w + d2i;

  float ax = 0.f, ay = 0.f;
#pragma unroll
  for (int k = 0; k < KK; ++k) {
    f32x2 xv = xp[(size_t)k * (DD / 2)];
    f32x2 wv = wp[(size_t)k * (DD / 2)];
    float dx = xv.x - wv.x;
    float dy = xv.y - wv.y;
    ax = fmaf(dx, dx, ax);
    ay = fmaf(dy, dy, ay);
  }

  // inv[s] = 1/(2*sigma^2), sigma = 1..5
  const float inv[SS] = {0.5f, 0.125f, 1.0f / 18.0f, 0.03125f, 0.02f};
#pragma unroll
  for (int s = 0; s < SS; ++s) {
    f32x2 e;
    e.x = expf(-ax * inv[s]);
    e.y = expf(-ay * inv[s]);
    ((f32x2*)kv)[((size_t)(s * BB + b)) * (DD / 2) + d2i] = e;
  }
}

__global__ __launch_bounds__(512) void rbf_bcast_kernel(
    const float* __restrict__ kv, float* __restrict__ out) {
  // One block per output row (s*BB+b); 512 threads * f32x4 = 2048 floats = D.
  // Each block writes KK*DD*4B = 401.4 KB fully sequentially (fill pattern).
  const int row = blockIdx.x;   // [0, SS*BB)
  const int t   = threadIdx.x;  // [0, 512)

  f32x4 e = ((const f32x4*)kv)[(size_t)row * (DD / 4) + t];
  f32x4* op = (f32x4*)out + (size_t)row * (KK * (DD / 4)) + t;
#pragma unroll
  for (int k = 0; k < KK; ++k) {
    op[(size_t)k * (DD / 4)] = e;
  }
}

extern "C" void kernel_launch(void* const* d_in, const int* in_sizes, int n_in,
                              void* d_out, int out_size, void* d_ws,
                              size_t ws_size, hipStream_t stream) {
  const float* x = (const float*)d_in[0];
  const float* w = (const float*)d_in[1];
  float* out = (float*)d_out;
  float* kv = (float*)d_ws;  // needs SS*BB*DD*4 = 5.24 MB

  rbf_kv_kernel<<<dim3(BB * 4), dim3(256), 0, stream>>>(x, w, kv);
  rbf_bcast_kernel<<<dim3(SS * BB), dim3(512), 0, stream>>>(kv, out);
}

// Round 13
// 293.642 us; speedup vs baseline: 1.0151x; 1.0151x over previous
//
#include <hip/hip_runtime.h>

// x (B,K,D) f32, w (1,K,D) f32 -> out (S*B, K, D) f32
// out[s*B+b, k, d] = exp(-d2[b,d] * inv[s]),  d2[b,d] = sum_k (x[b,k,d]-w[k,d])^2
//
// Fused single-pass (x read once). k-split pair scheme: threads t and t+128
// share one f32x4 d-slot; each reduces half of K, partials exchanged via LDS,
// then the 5*49 broadcast rows are split between the pair (lo: k<25, hi: k>=25).
// Stores are f32x4 (1 KB per wave-instr — same width as the harness fill that
// sustains 6.2 TB/s), occupancy 8 waves/CU.
#define BB 128
#define KK 49
#define DD 2048
#define SS 5
#define D4 (DD / 4)  // 512 f32x4 per row

typedef float f32x4 __attribute__((ext_vector_type(4)));

__global__ __launch_bounds__(256) void rbf_fused_kernel(
    const float* __restrict__ x, const float* __restrict__ w,
    float* __restrict__ out) {
  const int chunk = blockIdx.x & 3;          // 4 chunks of 128 f32x4
  const int b     = blockIdx.x >> 2;
  const int tl    = threadIdx.x & 127;
  const int hi    = threadIdx.x >> 7;        // 0: k in [0,25), 1: k in [25,49)
  const int s4    = chunk * 128 + tl;        // f32x4 index within row, [0,512)

  const f32x4* xp = (const f32x4*)x + (size_t)b * (KK * D4) + s4;
  const f32x4* wp = (const f32x4*)w + s4;

  f32x4 acc = {0.f, 0.f, 0.f, 0.f};
  if (!hi) {
#pragma unroll
    for (int k = 0; k < 25; ++k) {
      f32x4 xv = xp[k * D4];
      f32x4 wv = wp[k * D4];
      f32x4 d  = xv - wv;
      acc += d * d;
    }
  } else {
#pragma unroll
    for (int k = 25; k < 49; ++k) {
      f32x4 xv = xp[k * D4];
      f32x4 wv = wp[k * D4];
      f32x4 d  = xv - wv;
      acc += d * d;
    }
  }

  // exchange partials within the pair (wave-uniform branch, one barrier)
  __shared__ f32x4 part[2][128];
  part[hi][tl] = acc;
  __syncthreads();
  f32x4 d2 = acc + part[hi ^ 1][tl];

  // inv[s] = 1/(2*sigma^2), sigma = 1..5
  const float inv[SS] = {0.5f, 0.125f, 1.0f / 18.0f, 0.03125f, 0.02f};
  f32x4 e[SS];
#pragma unroll
  for (int s = 0; s < SS; ++s) {
    e[s].x = expf(-d2.x * inv[s]);
    e[s].y = expf(-d2.y * inv[s]);
    e[s].z = expf(-d2.z * inv[s]);
    e[s].w = expf(-d2.w * inv[s]);
  }

  // broadcast stores, k-range split between the pair
  if (!hi) {
#pragma unroll
    for (int s = 0; s < SS; ++s) {
      f32x4* op = (f32x4*)out + ((size_t)(s * BB + b) * KK) * D4 + s4;
#pragma unroll
      for (int k = 0; k < 25; ++k) op[k * D4] = e[s];
    }
  } else {
#pragma unroll
    for (int s = 0; s < SS; ++s) {
      f32x4* op = (f32x4*)out + ((size_t)(s * BB + b) * KK) * D4 + s4;
#pragma unroll
      for (int k = 25; k < 49; ++k) op[k * D4] = e[s];
    }
  }
}

extern "C" void kernel_launch(void* const* d_in, const int* in_sizes, int n_in,
                              void* d_out, int out_size, void* d_ws,
                              size_t ws_size, hipStream_t stream) {
  const float* x = (const float*)d_in[0];
  const float* w = (const float*)d_in[1];
  float* out = (float*)d_out;
  rbf_fused_kernel<<<dim3(BB * 4), dim3(256), 0, stream>>>(x, w, out);
}

// Round 15
// 288.399 us; speedup vs baseline: 1.0336x; 1.0182x over previous
//
#include <hip/hip_runtime.h>

// x (B,K,D) f32, w (1,K,D) f32 -> out (S*B, K, D) f32
// out[s*B+b, k, d] = exp(-d2[b,d] * inv[s]),  d2[b,d] = sum_k (x[b,k,d]-w[k,d])^2
//
// Fused, NT stores, 2048 blocks x 128 threads = 16 waves/CU (2x r7's TLP).
// r14's 1024x256 variant had an indexing bug (chunk*128 + tid with tid<256
// overlapped slots); this geometry is bijective: 8 chunks of 128 f32x2,
// 128 threads each.
#define BB 128
#define KK 49
#define DD 2048
#define SS 5
#define D2N (DD / 2)  // 1024 f32x2 per row

typedef float f32x2 __attribute__((ext_vector_type(2)));

__global__ __launch_bounds__(128) void rbf_broadcast_kernel(
    const float* __restrict__ x, const float* __restrict__ w,
    float* __restrict__ out) {
  const int chunk = blockIdx.x & 7;                  // 8 chunks of 128 f32x2
  const int b     = blockIdx.x >> 3;
  const int d2i   = chunk * 128 + (int)threadIdx.x;  // [0, 1024), bijective

  const f32x2* xp = (const f32x2*)x + (size_t)b * (KK * D2N) + d2i;
  const f32x2* wp = (const f32x2*)w + d2i;

  float ax = 0.f, ay = 0.f;
#pragma unroll
  for (int k = 0; k < KK; ++k) {
    f32x2 xv = xp[(size_t)k * D2N];
    f32x2 wv = wp[(size_t)k * D2N];
    float dx = xv.x - wv.x;
    float dy = xv.y - wv.y;
    ax = fmaf(dx, dx, ax);
    ay = fmaf(dy, dy, ay);
  }

  // inv[s] = 1/(2*sigma^2), sigma = 1..5
  const float inv[SS] = {0.5f, 0.125f, 1.0f / 18.0f, 0.03125f, 0.02f};

#pragma unroll
  for (int s = 0; s < SS; ++s) {
    f32x2 e;
    e.x = expf(-ax * inv[s]);
    e.y = expf(-ay * inv[s]);
    f32x2* op = (f32x2*)out + ((size_t)(s * BB + b) * KK) * D2N + d2i;
#pragma unroll
    for (int k = 0; k < KK; ++k) {
      __builtin_nontemporal_store(e, op + (size_t)k * D2N);
    }
  }
}

extern "C" void kernel_launch(void* const* d_in, const int* in_sizes, int n_in,
                              void* d_out, int out_size, void* d_ws,
                              size_t ws_size, hipStream_t stream) {
  const float* x = (const float*)d_in[0];
  const float* w = (const float*)d_in[1];
  float* out = (float*)d_out;
  dim3 grid(BB * 8);
  dim3 block(128);
  rbf_broadcast_kernel<<<grid, block, 0, stream>>>(x, w, out);
}